// Round 9
// baseline (1199.052 us; speedup 1.0000x reference)
//
#include <hip/hip_runtime.h>

typedef _Float16 half8 __attribute__((ext_vector_type(8)));
typedef _Float16 half4 __attribute__((ext_vector_type(4)));
typedef _Float16 half2v __attribute__((ext_vector_type(2)));
typedef float f4 __attribute__((ext_vector_type(4)));
typedef float f2 __attribute__((ext_vector_type(2)));

#define NBK 1024     // bucket table size (256 nodes/bucket, supports N<=262144)
#define NBLK 128     // blocks in hist/scatter passes (fixed edge chunking)

// ---------------- graph preprocessing (NO global atomics) ----------------

__global__ __launch_bounds__(256)
void k_bhist(const int* __restrict__ ei, int E, int chunk,
             int* __restrict__ hb) {
  __shared__ int hd[NBK], hs[NBK];
  int t = threadIdx.x, blk = blockIdx.x;
  for (int i = t; i < NBK; i += 256) { hd[i] = 0; hs[i] = 0; }
  __syncthreads();
  int start = blk * chunk, end = min(E, start + chunk);
  for (int i = start + t; i < end; i += 256) {
    int dst = ei[i];
    int src = ei[E + i];
    atomicAdd(&hd[dst >> 8], 1);
    atomicAdd(&hs[src >> 8], 1);
  }
  __syncthreads();
  for (int i = t; i < NBK; i += 256) {
    hb[blk * NBK + i] = hd[i];
    hb[(NBLK + blk) * NBK + i] = hs[i];
  }
}

__global__ void k_colscan(int* __restrict__ hb, int* __restrict__ totals) {
  int tid = blockIdx.x * 256 + threadIdx.x;      // 0..2047
  int* tab = hb + (tid >> 10) * (NBLK * NBK);
  int j = tid & (NBK - 1);
  int run = 0;
  for (int b = 0; b < NBLK; ++b) {
    int idx = b * NBK + j;
    int v = tab[idx];
    tab[idx] = run;
    run += v;
  }
  totals[tid] = run;
}

__global__ void k_bscan2(const int* __restrict__ totals, int* __restrict__ boffs,
                         int* __restrict__ soffs, int* __restrict__ offs,
                         int N, int E) {
  __shared__ int s[NBK];
  int t = threadIdx.x;                            // 1024 threads
  int v = totals[t];
  s[t] = v;
  __syncthreads();
  for (int off = 1; off < NBK; off <<= 1) {
    int x = (t >= off) ? s[t - off] : 0;
    __syncthreads();
    s[t] += x;
    __syncthreads();
  }
  boffs[t] = s[t] - v;
  if (t == NBK - 1) boffs[NBK] = s[t];
  __syncthreads();
  int v2 = totals[NBK + t];
  s[t] = v2;
  __syncthreads();
  for (int off = 1; off < NBK; off <<= 1) {
    int x = (t >= off) ? s[t - off] : 0;
    __syncthreads();
    s[t] += x;
    __syncthreads();
  }
  soffs[t] = s[t] - v2;
  if (t == NBK - 1) soffs[NBK] = s[t];
  if (t == 0) offs[N] = E;
}

__global__ __launch_bounds__(256)
void k_bscatter(const int* __restrict__ ei, int E, int chunk,
                const int* __restrict__ hb, const int* __restrict__ boffs,
                const int* __restrict__ soffs,
                unsigned long long* __restrict__ pairs,
                unsigned char* __restrict__ srcb) {
  __shared__ int based[NBK], posd[NBK], bases[NBK], poss[NBK];
  int t = threadIdx.x, blk = blockIdx.x;
  for (int i = t; i < NBK; i += 256) {
    based[i] = hb[blk * NBK + i] + boffs[i];
    posd[i] = 0;
    bases[i] = hb[(NBLK + blk) * NBK + i] + soffs[i];
    poss[i] = 0;
  }
  __syncthreads();
  int start = blk * chunk, end = min(E, start + chunk);
  for (int i = start + t; i < end; i += 256) {
    int dst = ei[i];
    int src = ei[E + i];
    int bd = dst >> 8, bs = src >> 8;
    int p = atomicAdd(&posd[bd], 1);
    pairs[based[bd] + p] =
        ((unsigned long long)(unsigned)src << 32) | (unsigned)dst;
    int q = atomicAdd(&poss[bs], 1);
    srcb[bases[bs] + q] = (unsigned char)(src & 255);
  }
}

__global__ __launch_bounds__(256)
void k_deg(const unsigned char* __restrict__ srcb, const int* __restrict__ soffs,
           float* __restrict__ dis, int N) {
  __shared__ int h[256];
  int b = blockIdx.x, t = threadIdx.x;
  h[t] = 0;
  __syncthreads();
  int lo = soffs[b], hi = soffs[b + 1];
  for (int i = lo + t; i < hi; i += 256) atomicAdd(&h[srcb[i]], 1);
  __syncthreads();
  int v = (b << 8) + t;
  if (v < N) dis[v] = rsqrtf((float)(h[t] + 1));
}

__global__ __launch_bounds__(256)
void k_fscatter(const unsigned long long* __restrict__ pairs,
                const int* __restrict__ boffs,
                int* __restrict__ offs, int* __restrict__ srcs, int N) {
  __shared__ int h[256], sc[256], cur[256];
  int b = blockIdx.x, t = threadIdx.x;
  h[t] = 0;
  __syncthreads();
  int pl = boffs[b], ph = boffs[b + 1];
  for (int i = pl + t; i < ph; i += 256)
    atomicAdd(&h[(int)(pairs[i] & 255ull)], 1);
  __syncthreads();
  sc[t] = h[t];
  __syncthreads();
  for (int off = 1; off < 256; off <<= 1) {
    int x = (t >= off) ? sc[t - off] : 0;
    __syncthreads();
    sc[t] += x;
    __syncthreads();
  }
  int excl = sc[t] - h[t];
  int v = (b << 8) + t;
  if (v < N) offs[v] = pl + excl;
  cur[t] = pl + excl;
  __syncthreads();
  for (int i = pl + t; i < ph; i += 256) {
    unsigned long long pk = pairs[i];
    int p = atomicAdd(&cur[(int)(pk & 255ull)], 1);
    srcs[p] = (int)(unsigned)(pk >> 32);
  }
}

// W (128x128 fp32 row-major, W[k][c]) -> Wt fp16 transposed: Wt[c][k]
__global__ void k_prepw(const float* __restrict__ W0, const float* __restrict__ W1,
                        const float* __restrict__ W2, _Float16* __restrict__ Wt) {
  int i = blockIdx.x * blockDim.x + threadIdx.x;   // 0..49151
  int m = i >> 14;
  int j = i & 16383;
  int c = j >> 7, k = j & 127;
  const float* W = (m == 0) ? W0 : (m == 1) ? W1 : W2;
  Wt[i] = (_Float16)W[k * 128 + c];
}

// ---------------- fp16 MFMA GEMM + dis-scale epilogue ----------------
// hws is SLICE-MAJOR: hws[sl][v][16 feats], sl = feature/16, slice stride N*16
// halves (3.2 MB contiguous) -> each slice is L2-resident on one XCD in agg.

#define LDH 136   // padded halves per row -> conflict-free ds_read_b128

__global__ __launch_bounds__(256, 2)
void k_gemm(const float* __restrict__ in, int in_stride, int do_relu,
            const _Float16* __restrict__ Wt_g, const float* __restrict__ dis,
            _Float16* __restrict__ hws, int N) {
  __shared__ _Float16 Wt[128 * LDH];
  int t = threadIdx.x;
  int rbase = blockIdx.x * 128;
  size_t slst = (size_t)N * 16;   // slice stride in halves

#pragma unroll
  for (int i = 0; i < 8; ++i) {
    int s = t + i * 256;
    int c = s >> 4, kh = s & 15;
    half8 w = ((const half8*)Wt_g)[s];
    *(half8*)&Wt[c * LDH + kh * 8] = w;
  }
  __syncthreads();

  int wv = t >> 6, lane = t & 63;
  int r0 = wv * 32;
  int lr = lane & 15, lg = lane >> 4;

  f4 acc[2][8];
#pragma unroll
  for (int fm = 0; fm < 2; ++fm)
#pragma unroll
    for (int fn = 0; fn < 8; ++fn) acc[fm][fn] = (f4){0.f, 0.f, 0.f, 0.f};

#pragma unroll
  for (int ks = 0; ks < 4; ++ks) {
    int k0 = ks * 32 + lg * 8;
    half8 a[8];
#pragma unroll
    for (int fn = 0; fn < 8; ++fn)
      a[fn] = *(const half8*)&Wt[(fn * 16 + lr) * LDH + k0];
#pragma unroll
    for (int fm = 0; fm < 2; ++fm) {
      int gr = rbase + r0 + fm * 16 + lr;
      float4 v0 = make_float4(0.f, 0.f, 0.f, 0.f);
      float4 v1 = make_float4(0.f, 0.f, 0.f, 0.f);
      if (gr < N) {
        const float* pr = in + (size_t)gr * in_stride + k0;
        v0 = *(const float4*)pr;
        v1 = *(const float4*)(pr + 4);
      }
      if (do_relu) {
        v0.x = fmaxf(v0.x, 0.f); v0.y = fmaxf(v0.y, 0.f);
        v0.z = fmaxf(v0.z, 0.f); v0.w = fmaxf(v0.w, 0.f);
        v1.x = fmaxf(v1.x, 0.f); v1.y = fmaxf(v1.y, 0.f);
        v1.z = fmaxf(v1.z, 0.f); v1.w = fmaxf(v1.w, 0.f);
      }
      half8 b;
      b[0] = (_Float16)v0.x; b[1] = (_Float16)v0.y;
      b[2] = (_Float16)v0.z; b[3] = (_Float16)v0.w;
      b[4] = (_Float16)v1.x; b[5] = (_Float16)v1.y;
      b[6] = (_Float16)v1.z; b[7] = (_Float16)v1.w;
#pragma unroll
      for (int fn = 0; fn < 8; ++fn)
        acc[fm][fn] = __builtin_amdgcn_mfma_f32_16x16x32_f16(a[fn], b, acc[fm][fn], 0, 0, 0);
    }
  }

#pragma unroll
  for (int fm = 0; fm < 2; ++fm) {
    int gr = rbase + r0 + fm * 16 + lr;
    if (gr >= N) continue;
    float dv = dis[gr];
#pragma unroll
    for (int fn = 0; fn < 8; ++fn) {
      f4 d = acc[fm][fn];
      half4 hv;
      hv[0] = (_Float16)(d[0] * dv);
      hv[1] = (_Float16)(d[1] * dv);
      hv[2] = (_Float16)(d[2] * dv);
      hv[3] = (_Float16)(d[3] * dv);
      *(half4*)(hws + (size_t)fn * slst + (size_t)gr * 16 + lg * 4) = hv;
    }
  }
}

// ---------------- aggregation: feature-sliced, wave-cooperative ----------------
// slice = blockIdx.x & 7: consecutive blocks round-robin across XCDs, so each
// slice's blocks land on one XCD and its 3.2MB slice stays L2-resident (pure
// locality hint; correctness independent of placement). One wave per dst node:
// lane = (edge-group g=lane>>3, feat-pair fp=lane&7). Group g handles items
// g, g+8, ... (item 0 = self); 8 lanes/group read 32B contiguous. 3 shfl_xor
// reduce groups; lanes g==0 store one full 64B line of out.
#define AGG_NPB 256   // nodes per block (64 per wave)

__global__ __launch_bounds__(256)
void k_agg3(const _Float16* __restrict__ hws, const int* __restrict__ offs,
            const int* __restrict__ srcs, const float* __restrict__ dis,
            const float* __restrict__ bias, float* __restrict__ out,
            int N, int layer) {
  int sl = blockIdx.x & 7;
  int chunkId = blockIdx.x >> 3;
  int wv = threadIdx.x >> 6, lane = threadIdx.x & 63;
  int fp = lane & 7;      // feature pair (2 floats)
  int g  = lane >> 3;     // edge group
  size_t slst = (size_t)N * 16;
  const _Float16* hsl = hws + (size_t)sl * slst;
  int f0 = sl * 16;
  f2 bb = *(const f2*)(bias + f0 + fp * 2);

  int vend = min(N, chunkId * AGG_NPB + AGG_NPB);
  for (int v = chunkId * AGG_NPB + wv; v < vend; v += 4) {
    int e0 = __builtin_nontemporal_load(&offs[v]);
    int e1 = __builtin_nontemporal_load(&offs[v + 1]);
    int cnt = e1 - e0 + 1;                       // +1 = self item at slot 0
    float ax = 0.f, ay = 0.f;
    for (int it = g; it < cnt; it += 8) {
      int s = (it == 0) ? v : __builtin_nontemporal_load(&srcs[e0 + it - 1]);
      uint u = *(const uint*)(hsl + (size_t)s * 16 + fp * 2);
      half2v h = __builtin_bit_cast(half2v, u);
      ax += (float)h[0];
      ay += (float)h[1];
    }
#pragma unroll
    for (int off = 8; off < 64; off <<= 1) {
      ax += __shfl_xor(ax, off);
      ay += __shfl_xor(ay, off);
    }
    if (g == 0) {
      float dv = dis[v];
      f2 o;
      o[0] = fmaf(dv, ax, bb[0]);
      o[1] = fmaf(dv, ay, bb[1]);
      __builtin_nontemporal_store(o, (f2*)(out + (size_t)v * 384 + layer * 128 + f0 + fp * 2));
    }
  }
}

// ---------------- launch ----------------

extern "C" void kernel_launch(void* const* d_in, const int* in_sizes, int n_in,
                              void* d_out, int out_size, void* d_ws, size_t ws_size,
                              hipStream_t stream) {
  const float* x  = (const float*)d_in[0];
  const int*   ei = (const int*)d_in[1];
  const float* W0 = (const float*)d_in[2];
  const float* b0 = (const float*)d_in[3];
  const float* W1 = (const float*)d_in[4];
  const float* b1 = (const float*)d_in[5];
  const float* W2 = (const float*)d_in[6];
  const float* b2 = (const float*)d_in[7];
  float* out = (float*)d_out;

  int N = in_sizes[0] / 128;
  int E = in_sizes[1] / 2;
  int nb = (N + 255) >> 8;                       // active buckets
  int chunk = (((E + NBLK - 1) / NBLK) + 255) & ~255;

  char* p = (char*)d_ws;
  auto alloc = [&](size_t sz) { char* r = p; p += (sz + 255) & ~(size_t)255; return r; };
  _Float16* hws  = (_Float16*)alloc((size_t)N * 128 * 2);
  float* dis     = (float*)alloc((size_t)N * 4);
  int*   offs    = (int*)alloc((size_t)(N + 1) * 4);
  int*   srcs    = (int*)alloc((size_t)E * 4);
  _Float16* Wt   = (_Float16*)alloc((size_t)3 * 128 * 128 * 2);
  int*   hb      = (int*)alloc((size_t)2 * NBLK * NBK * 4);
  int*   totals  = (int*)alloc((size_t)2 * NBK * 4);
  int*   boffs   = (int*)alloc((size_t)(NBK + 1) * 4);
  int*   soffs   = (int*)alloc((size_t)(NBK + 1) * 4);
  unsigned long long* pairs = (unsigned long long*)alloc((size_t)E * 8);
  unsigned char* srcb = (unsigned char*)alloc((size_t)E);

  k_bhist<<<NBLK, 256, 0, stream>>>(ei, E, chunk, hb);
  k_colscan<<<8, 256, 0, stream>>>(hb, totals);
  k_bscan2<<<1, 1024, 0, stream>>>(totals, boffs, soffs, offs, N, E);
  k_bscatter<<<NBLK, 256, 0, stream>>>(ei, E, chunk, hb, boffs, soffs, pairs, srcb);
  k_deg<<<nb, 256, 0, stream>>>(srcb, soffs, dis, N);
  k_fscatter<<<nb, 256, 0, stream>>>(pairs, boffs, offs, srcs, N);
  k_prepw<<<192, 256, 0, stream>>>(W0, W1, W2, Wt);

  int gG = (N + 127) / 128;
  int gA = 8 * ((N + AGG_NPB - 1) / AGG_NPB);

  // layer 0
  k_gemm<<<gG, 256, 0, stream>>>(x, 128, 0, Wt, dis, hws, N);
  k_agg3<<<gA, 256, 0, stream>>>(hws, offs, srcs, dis, b0, out, N, 0);
  // layer 1: input = relu(out[:,0,:]) (stride 384)
  k_gemm<<<gG, 256, 0, stream>>>(out, 384, 1, Wt + 16384, dis, hws, N);
  k_agg3<<<gA, 256, 0, stream>>>(hws, offs, srcs, dis, b1, out, N, 1);
  // layer 2: input = relu(out[:,1,:])
  k_gemm<<<gG, 256, 0, stream>>>(out + 128, 384, 1, Wt + 32768, dis, hws, N);
  k_agg3<<<gA, 256, 0, stream>>>(hws, offs, srcs, dis, b2, out, N, 2);
}

// Round 10
// 724.118 us; speedup vs baseline: 1.6559x; 1.6559x over previous
//
#include <hip/hip_runtime.h>

typedef _Float16 half8 __attribute__((ext_vector_type(8)));
typedef _Float16 half4 __attribute__((ext_vector_type(4)));
typedef float f4 __attribute__((ext_vector_type(4)));

#define NBK 1024     // bucket table size (256 nodes/bucket, supports N<=262144)
#define NBLK 128     // blocks in hist/scatter passes (fixed edge chunking)

// ---------------- graph preprocessing (NO global atomics) ----------------

__global__ __launch_bounds__(256)
void k_bhist(const int* __restrict__ ei, int E, int chunk,
             int* __restrict__ hb) {
  __shared__ int hd[NBK], hs[NBK];
  int t = threadIdx.x, blk = blockIdx.x;
  for (int i = t; i < NBK; i += 256) { hd[i] = 0; hs[i] = 0; }
  __syncthreads();
  int start = blk * chunk, end = min(E, start + chunk);
  for (int i = start + t; i < end; i += 256) {
    int dst = ei[i];
    int src = ei[E + i];
    atomicAdd(&hd[dst >> 8], 1);
    atomicAdd(&hs[src >> 8], 1);
  }
  __syncthreads();
  for (int i = t; i < NBK; i += 256) {
    hb[blk * NBK + i] = hd[i];
    hb[(NBLK + blk) * NBK + i] = hs[i];
  }
}

__global__ void k_colscan(int* __restrict__ hb, int* __restrict__ totals) {
  int tid = blockIdx.x * 256 + threadIdx.x;      // 0..2047
  int* tab = hb + (tid >> 10) * (NBLK * NBK);
  int j = tid & (NBK - 1);
  int run = 0;
  for (int b = 0; b < NBLK; ++b) {
    int idx = b * NBK + j;
    int v = tab[idx];
    tab[idx] = run;
    run += v;
  }
  totals[tid] = run;
}

__global__ void k_bscan2(const int* __restrict__ totals, int* __restrict__ boffs,
                         int* __restrict__ soffs, int* __restrict__ offs,
                         int N, int E) {
  __shared__ int s[NBK];
  int t = threadIdx.x;                            // 1024 threads
  int v = totals[t];
  s[t] = v;
  __syncthreads();
  for (int off = 1; off < NBK; off <<= 1) {
    int x = (t >= off) ? s[t - off] : 0;
    __syncthreads();
    s[t] += x;
    __syncthreads();
  }
  boffs[t] = s[t] - v;
  if (t == NBK - 1) boffs[NBK] = s[t];
  __syncthreads();
  int v2 = totals[NBK + t];
  s[t] = v2;
  __syncthreads();
  for (int off = 1; off < NBK; off <<= 1) {
    int x = (t >= off) ? s[t - off] : 0;
    __syncthreads();
    s[t] += x;
    __syncthreads();
  }
  soffs[t] = s[t] - v2;
  if (t == NBK - 1) soffs[NBK] = s[t];
  if (t == 0) offs[N] = E;
}

__global__ __launch_bounds__(256)
void k_bscatter(const int* __restrict__ ei, int E, int chunk,
                const int* __restrict__ hb, const int* __restrict__ boffs,
                const int* __restrict__ soffs,
                unsigned long long* __restrict__ pairs,
                unsigned char* __restrict__ srcb) {
  __shared__ int based[NBK], posd[NBK], bases[NBK], poss[NBK];
  int t = threadIdx.x, blk = blockIdx.x;
  for (int i = t; i < NBK; i += 256) {
    based[i] = hb[blk * NBK + i] + boffs[i];
    posd[i] = 0;
    bases[i] = hb[(NBLK + blk) * NBK + i] + soffs[i];
    poss[i] = 0;
  }
  __syncthreads();
  int start = blk * chunk, end = min(E, start + chunk);
  for (int i = start + t; i < end; i += 256) {
    int dst = ei[i];
    int src = ei[E + i];
    int bd = dst >> 8, bs = src >> 8;
    int p = atomicAdd(&posd[bd], 1);
    pairs[based[bd] + p] =
        ((unsigned long long)(unsigned)src << 32) | (unsigned)dst;
    int q = atomicAdd(&poss[bs], 1);
    srcb[bases[bs] + q] = (unsigned char)(src & 255);
  }
}

__global__ __launch_bounds__(256)
void k_deg(const unsigned char* __restrict__ srcb, const int* __restrict__ soffs,
           float* __restrict__ dis, int N) {
  __shared__ int h[256];
  int b = blockIdx.x, t = threadIdx.x;
  h[t] = 0;
  __syncthreads();
  int lo = soffs[b], hi = soffs[b + 1];
  for (int i = lo + t; i < hi; i += 256) atomicAdd(&h[srcb[i]], 1);
  __syncthreads();
  int v = (b << 8) + t;
  if (v < N) dis[v] = rsqrtf((float)(h[t] + 1));
}

__global__ __launch_bounds__(256)
void k_fscatter(const unsigned long long* __restrict__ pairs,
                const int* __restrict__ boffs,
                int* __restrict__ offs, int* __restrict__ srcs, int N) {
  __shared__ int h[256], sc[256], cur[256];
  int b = blockIdx.x, t = threadIdx.x;
  h[t] = 0;
  __syncthreads();
  int pl = boffs[b], ph = boffs[b + 1];
  for (int i = pl + t; i < ph; i += 256)
    atomicAdd(&h[(int)(pairs[i] & 255ull)], 1);
  __syncthreads();
  sc[t] = h[t];
  __syncthreads();
  for (int off = 1; off < 256; off <<= 1) {
    int x = (t >= off) ? sc[t - off] : 0;
    __syncthreads();
    sc[t] += x;
    __syncthreads();
  }
  int excl = sc[t] - h[t];
  int v = (b << 8) + t;
  if (v < N) offs[v] = pl + excl;
  cur[t] = pl + excl;
  __syncthreads();
  for (int i = pl + t; i < ph; i += 256) {
    unsigned long long pk = pairs[i];
    int p = atomicAdd(&cur[(int)(pk & 255ull)], 1);
    srcs[p] = (int)(unsigned)(pk >> 32);
  }
}

// W (128x128 fp32 row-major, W[k][c]) -> Wt fp16 transposed: Wt[c][k]
__global__ void k_prepw(const float* __restrict__ W0, const float* __restrict__ W1,
                        const float* __restrict__ W2, _Float16* __restrict__ Wt) {
  int i = blockIdx.x * blockDim.x + threadIdx.x;   // 0..49151
  int m = i >> 14;
  int j = i & 16383;
  int c = j >> 7, k = j & 127;
  const float* W = (m == 0) ? W0 : (m == 1) ? W1 : W2;
  Wt[i] = (_Float16)W[k * 128 + c];
}

// ---------------- fp16 MFMA GEMM + dis-scale epilogue ----------------
// hws is SLICE-MAJOR with 32-feat slices: hws[sl][v][32], sl = feature/32,
// slice stride N*32 halves (6.4 MB). Row = 64 B = one cache line.

#define LDH 136   // padded halves per row -> conflict-free ds_read_b128

__global__ __launch_bounds__(256, 2)
void k_gemm(const float* __restrict__ in, int in_stride, int do_relu,
            const _Float16* __restrict__ Wt_g, const float* __restrict__ dis,
            _Float16* __restrict__ hws, int N) {
  __shared__ _Float16 Wt[128 * LDH];
  int t = threadIdx.x;
  int rbase = blockIdx.x * 128;
  size_t slst = (size_t)N * 32;   // slice stride in halves

#pragma unroll
  for (int i = 0; i < 8; ++i) {
    int s = t + i * 256;
    int c = s >> 4, kh = s & 15;
    half8 w = ((const half8*)Wt_g)[s];
    *(half8*)&Wt[c * LDH + kh * 8] = w;
  }
  __syncthreads();

  int wv = t >> 6, lane = t & 63;
  int r0 = wv * 32;
  int lr = lane & 15, lg = lane >> 4;

  f4 acc[2][8];
#pragma unroll
  for (int fm = 0; fm < 2; ++fm)
#pragma unroll
    for (int fn = 0; fn < 8; ++fn) acc[fm][fn] = (f4){0.f, 0.f, 0.f, 0.f};

#pragma unroll
  for (int ks = 0; ks < 4; ++ks) {
    int k0 = ks * 32 + lg * 8;
    half8 a[8];
#pragma unroll
    for (int fn = 0; fn < 8; ++fn)
      a[fn] = *(const half8*)&Wt[(fn * 16 + lr) * LDH + k0];
#pragma unroll
    for (int fm = 0; fm < 2; ++fm) {
      int gr = rbase + r0 + fm * 16 + lr;
      float4 v0 = make_float4(0.f, 0.f, 0.f, 0.f);
      float4 v1 = make_float4(0.f, 0.f, 0.f, 0.f);
      if (gr < N) {
        const float* pr = in + (size_t)gr * in_stride + k0;
        v0 = *(const float4*)pr;
        v1 = *(const float4*)(pr + 4);
      }
      if (do_relu) {
        v0.x = fmaxf(v0.x, 0.f); v0.y = fmaxf(v0.y, 0.f);
        v0.z = fmaxf(v0.z, 0.f); v0.w = fmaxf(v0.w, 0.f);
        v1.x = fmaxf(v1.x, 0.f); v1.y = fmaxf(v1.y, 0.f);
        v1.z = fmaxf(v1.z, 0.f); v1.w = fmaxf(v1.w, 0.f);
      }
      half8 b;
      b[0] = (_Float16)v0.x; b[1] = (_Float16)v0.y;
      b[2] = (_Float16)v0.z; b[3] = (_Float16)v0.w;
      b[4] = (_Float16)v1.x; b[5] = (_Float16)v1.y;
      b[6] = (_Float16)v1.z; b[7] = (_Float16)v1.w;
#pragma unroll
      for (int fn = 0; fn < 8; ++fn)
        acc[fm][fn] = __builtin_amdgcn_mfma_f32_16x16x32_f16(a[fn], b, acc[fm][fn], 0, 0, 0);
    }
  }

#pragma unroll
  for (int fm = 0; fm < 2; ++fm) {
    int gr = rbase + r0 + fm * 16 + lr;
    if (gr >= N) continue;
    float dv = dis[gr];
#pragma unroll
    for (int fn = 0; fn < 8; ++fn) {
      f4 d = acc[fm][fn];
      half4 hv;
      hv[0] = (_Float16)(d[0] * dv);
      hv[1] = (_Float16)(d[1] * dv);
      hv[2] = (_Float16)(d[2] * dv);
      hv[3] = (_Float16)(d[3] * dv);
      int c = fn * 16 + lg * 4;        // global column 0..127
      int sl = c >> 5;                 // 32-feat slice
      int cw = c & 31;                 // col within slice
      *(half4*)(hws + (size_t)sl * slst + (size_t)gr * 32 + cw) = hv;
    }
  }
}

// ---------------- aggregation: 32-feat slices, full-line wave gathers --------
// slice = blockIdx&3 -> XCDs {sl, sl+4} (locality hint only). One NODE per
// wave: lane = (q=lane>>4: 16B chunk of the 64B row, j=lane&15: edge slot).
// One gather instruction covers 16 edges x 64B full lines (~2 instr/node).
// Reduce across j = shfl_xor 1/2/4/8 (within 16-lane rows). srcs/offs
// nontemporal; out stores nontemporal (don't evict the resident slice).
#define AGG_NPB 128   // nodes per block (32 per wave)

__global__ __launch_bounds__(256)
void k_agg7(const _Float16* __restrict__ hws, const int* __restrict__ offs,
            const int* __restrict__ srcs, const float* __restrict__ dis,
            const float* __restrict__ bias, float* __restrict__ out,
            int N, int layer) {
  int sl = blockIdx.x & 3;
  int chunkId = blockIdx.x >> 2;
  int wv = threadIdx.x >> 6, lane = threadIdx.x & 63;
  int q = lane >> 4;      // 16B chunk (8 feats) of the 64B row
  int j = lane & 15;      // edge slot
  size_t slst = (size_t)N * 32;
  const _Float16* hsl = hws + (size_t)sl * slst;
  int f0 = sl * 32;

  int vend = min(N, chunkId * AGG_NPB + AGG_NPB);
  for (int v = chunkId * AGG_NPB + wv; v < vend; v += 4) {
    int e0 = __builtin_nontemporal_load(&offs[v]);
    int e1 = __builtin_nontemporal_load(&offs[v + 1]);

    float acc0 = 0.f, acc1 = 0.f, acc2 = 0.f, acc3 = 0.f;
    float acc4 = 0.f, acc5 = 0.f, acc6 = 0.f, acc7 = 0.f;
    if (j == 0) {   // self term, added once per (node, q-chunk)
      half8 r = *(const half8*)(hsl + (size_t)v * 32 + q * 8);
      acc0 = (float)r[0]; acc1 = (float)r[1]; acc2 = (float)r[2]; acc3 = (float)r[3];
      acc4 = (float)r[4]; acc5 = (float)r[5]; acc6 = (float)r[6]; acc7 = (float)r[7];
    }
    for (int e = e0 + j; e < e1; e += 16) {
      int s = __builtin_nontemporal_load(&srcs[e]);
      half8 r = *(const half8*)(hsl + (size_t)s * 32 + q * 8);
      acc0 += (float)r[0]; acc1 += (float)r[1]; acc2 += (float)r[2]; acc3 += (float)r[3];
      acc4 += (float)r[4]; acc5 += (float)r[5]; acc6 += (float)r[6]; acc7 += (float)r[7];
    }
#pragma unroll
    for (int off = 1; off < 16; off <<= 1) {
      acc0 += __shfl_xor(acc0, off); acc1 += __shfl_xor(acc1, off);
      acc2 += __shfl_xor(acc2, off); acc3 += __shfl_xor(acc3, off);
      acc4 += __shfl_xor(acc4, off); acc5 += __shfl_xor(acc5, off);
      acc6 += __shfl_xor(acc6, off); acc7 += __shfl_xor(acc7, off);
    }
    if (j == 0) {
      float dv = dis[v];
      const f4* bp = (const f4*)(bias + f0 + q * 8);
      f4 b0 = bp[0], b1 = bp[1];
      f4 o0, o1;
      o0[0] = fmaf(dv, acc0, b0[0]); o0[1] = fmaf(dv, acc1, b0[1]);
      o0[2] = fmaf(dv, acc2, b0[2]); o0[3] = fmaf(dv, acc3, b0[3]);
      o1[0] = fmaf(dv, acc4, b1[0]); o1[1] = fmaf(dv, acc5, b1[1]);
      o1[2] = fmaf(dv, acc6, b1[2]); o1[3] = fmaf(dv, acc7, b1[3]);
      f4* op = (f4*)(out + (size_t)v * 384 + layer * 128 + f0 + q * 8);
      __builtin_nontemporal_store(o0, op);
      __builtin_nontemporal_store(o1, op + 1);
    }
  }
}

// ---------------- launch ----------------

extern "C" void kernel_launch(void* const* d_in, const int* in_sizes, int n_in,
                              void* d_out, int out_size, void* d_ws, size_t ws_size,
                              hipStream_t stream) {
  const float* x  = (const float*)d_in[0];
  const int*   ei = (const int*)d_in[1];
  const float* W0 = (const float*)d_in[2];
  const float* b0 = (const float*)d_in[3];
  const float* W1 = (const float*)d_in[4];
  const float* b1 = (const float*)d_in[5];
  const float* W2 = (const float*)d_in[6];
  const float* b2 = (const float*)d_in[7];
  float* out = (float*)d_out;

  int N = in_sizes[0] / 128;
  int E = in_sizes[1] / 2;
  int nb = (N + 255) >> 8;                       // active buckets
  int chunk = (((E + NBLK - 1) / NBLK) + 255) & ~255;

  char* p = (char*)d_ws;
  auto alloc = [&](size_t sz) { char* r = p; p += (sz + 255) & ~(size_t)255; return r; };
  _Float16* hws  = (_Float16*)alloc((size_t)N * 128 * 2);
  float* dis     = (float*)alloc((size_t)N * 4);
  int*   offs    = (int*)alloc((size_t)(N + 1) * 4);
  int*   srcs    = (int*)alloc((size_t)E * 4);
  _Float16* Wt   = (_Float16*)alloc((size_t)3 * 128 * 128 * 2);
  int*   hb      = (int*)alloc((size_t)2 * NBLK * NBK * 4);
  int*   totals  = (int*)alloc((size_t)2 * NBK * 4);
  int*   boffs   = (int*)alloc((size_t)(NBK + 1) * 4);
  int*   soffs   = (int*)alloc((size_t)(NBK + 1) * 4);
  unsigned long long* pairs = (unsigned long long*)alloc((size_t)E * 8);
  unsigned char* srcb = (unsigned char*)alloc((size_t)E);

  k_bhist<<<NBLK, 256, 0, stream>>>(ei, E, chunk, hb);
  k_colscan<<<8, 256, 0, stream>>>(hb, totals);
  k_bscan2<<<1, 1024, 0, stream>>>(totals, boffs, soffs, offs, N, E);
  k_bscatter<<<NBLK, 256, 0, stream>>>(ei, E, chunk, hb, boffs, soffs, pairs, srcb);
  k_deg<<<nb, 256, 0, stream>>>(srcb, soffs, dis, N);
  k_fscatter<<<nb, 256, 0, stream>>>(pairs, boffs, offs, srcs, N);
  k_prepw<<<192, 256, 0, stream>>>(W0, W1, W2, Wt);

  int gG = (N + 127) / 128;
  int gA = 4 * ((N + AGG_NPB - 1) / AGG_NPB);

  // layer 0
  k_gemm<<<gG, 256, 0, stream>>>(x, 128, 0, Wt, dis, hws, N);
  k_agg7<<<gA, 256, 0, stream>>>(hws, offs, srcs, dis, b0, out, N, 0);
  // layer 1: input = relu(out[:,0,:]) (stride 384)
  k_gemm<<<gG, 256, 0, stream>>>(out, 384, 1, Wt + 16384, dis, hws, N);
  k_agg7<<<gA, 256, 0, stream>>>(hws, offs, srcs, dis, b1, out, N, 1);
  // layer 2: input = relu(out[:,1,:])
  k_gemm<<<gG, 256, 0, stream>>>(out + 128, 384, 1, Wt + 32768, dis, hws, N);
  k_agg7<<<gA, 256, 0, stream>>>(hws, offs, srcs, dis, b2, out, N, 2);
}

// Round 11
// 437.252 us; speedup vs baseline: 2.7422x; 1.6561x over previous
//
#include <hip/hip_runtime.h>

typedef _Float16 half8 __attribute__((ext_vector_type(8)));
typedef _Float16 half4 __attribute__((ext_vector_type(4)));
typedef _Float16 half2v __attribute__((ext_vector_type(2)));
typedef float f4 __attribute__((ext_vector_type(4)));

#define NBK 1024     // bucket table size (256 nodes/bucket, supports N<=262144)
#define NBLK 128     // blocks in hist/scatter passes (fixed edge chunking)

// ---------------- graph preprocessing (NO global atomics) ----------------

__global__ __launch_bounds__(256)
void k_bhist(const int* __restrict__ ei, int E, int chunk,
             int* __restrict__ hb) {
  __shared__ int hd[NBK], hs[NBK];
  int t = threadIdx.x, blk = blockIdx.x;
  for (int i = t; i < NBK; i += 256) { hd[i] = 0; hs[i] = 0; }
  __syncthreads();
  int start = blk * chunk, end = min(E, start + chunk);
  for (int i = start + t; i < end; i += 256) {
    int dst = ei[i];
    int src = ei[E + i];
    atomicAdd(&hd[dst >> 8], 1);
    atomicAdd(&hs[src >> 8], 1);
  }
  __syncthreads();
  for (int i = t; i < NBK; i += 256) {
    hb[blk * NBK + i] = hd[i];
    hb[(NBLK + blk) * NBK + i] = hs[i];
  }
}

__global__ void k_colscan(int* __restrict__ hb, int* __restrict__ totals) {
  int tid = blockIdx.x * 256 + threadIdx.x;      // 0..2047
  int* tab = hb + (tid >> 10) * (NBLK * NBK);
  int j = tid & (NBK - 1);
  int run = 0;
  for (int b = 0; b < NBLK; ++b) {
    int idx = b * NBK + j;
    int v = tab[idx];
    tab[idx] = run;
    run += v;
  }
  totals[tid] = run;
}

__global__ void k_bscan2(const int* __restrict__ totals, int* __restrict__ boffs,
                         int* __restrict__ soffs, int* __restrict__ offs,
                         int N, int E) {
  __shared__ int s[NBK];
  int t = threadIdx.x;                            // 1024 threads
  int v = totals[t];
  s[t] = v;
  __syncthreads();
  for (int off = 1; off < NBK; off <<= 1) {
    int x = (t >= off) ? s[t - off] : 0;
    __syncthreads();
    s[t] += x;
    __syncthreads();
  }
  boffs[t] = s[t] - v;
  if (t == NBK - 1) boffs[NBK] = s[t];
  __syncthreads();
  int v2 = totals[NBK + t];
  s[t] = v2;
  __syncthreads();
  for (int off = 1; off < NBK; off <<= 1) {
    int x = (t >= off) ? s[t - off] : 0;
    __syncthreads();
    s[t] += x;
    __syncthreads();
  }
  soffs[t] = s[t] - v2;
  if (t == NBK - 1) soffs[NBK] = s[t];
  if (t == 0) offs[N] = E;
}

__global__ __launch_bounds__(256)
void k_bscatter(const int* __restrict__ ei, int E, int chunk,
                const int* __restrict__ hb, const int* __restrict__ boffs,
                const int* __restrict__ soffs,
                unsigned long long* __restrict__ pairs,
                unsigned char* __restrict__ srcb) {
  __shared__ int based[NBK], posd[NBK], bases[NBK], poss[NBK];
  int t = threadIdx.x, blk = blockIdx.x;
  for (int i = t; i < NBK; i += 256) {
    based[i] = hb[blk * NBK + i] + boffs[i];
    posd[i] = 0;
    bases[i] = hb[(NBLK + blk) * NBK + i] + soffs[i];
    poss[i] = 0;
  }
  __syncthreads();
  int start = blk * chunk, end = min(E, start + chunk);
  for (int i = start + t; i < end; i += 256) {
    int dst = ei[i];
    int src = ei[E + i];
    int bd = dst >> 8, bs = src >> 8;
    int p = atomicAdd(&posd[bd], 1);
    pairs[based[bd] + p] =
        ((unsigned long long)(unsigned)src << 32) | (unsigned)dst;
    int q = atomicAdd(&poss[bs], 1);
    srcb[bases[bs] + q] = (unsigned char)(src & 255);
  }
}

__global__ __launch_bounds__(256)
void k_deg(const unsigned char* __restrict__ srcb, const int* __restrict__ soffs,
           float* __restrict__ dis, int N) {
  __shared__ int h[256];
  int b = blockIdx.x, t = threadIdx.x;
  h[t] = 0;
  __syncthreads();
  int lo = soffs[b], hi = soffs[b + 1];
  for (int i = lo + t; i < hi; i += 256) atomicAdd(&h[srcb[i]], 1);
  __syncthreads();
  int v = (b << 8) + t;
  if (v < N) dis[v] = rsqrtf((float)(h[t] + 1));
}

__global__ __launch_bounds__(256)
void k_fscatter(const unsigned long long* __restrict__ pairs,
                const int* __restrict__ boffs,
                int* __restrict__ offs, int* __restrict__ srcs, int N) {
  __shared__ int h[256], sc[256], cur[256];
  int b = blockIdx.x, t = threadIdx.x;
  h[t] = 0;
  __syncthreads();
  int pl = boffs[b], ph = boffs[b + 1];
  for (int i = pl + t; i < ph; i += 256)
    atomicAdd(&h[(int)(pairs[i] & 255ull)], 1);
  __syncthreads();
  sc[t] = h[t];
  __syncthreads();
  for (int off = 1; off < 256; off <<= 1) {
    int x = (t >= off) ? sc[t - off] : 0;
    __syncthreads();
    sc[t] += x;
    __syncthreads();
  }
  int excl = sc[t] - h[t];
  int v = (b << 8) + t;
  if (v < N) offs[v] = pl + excl;
  cur[t] = pl + excl;
  __syncthreads();
  for (int i = pl + t; i < ph; i += 256) {
    unsigned long long pk = pairs[i];
    int p = atomicAdd(&cur[(int)(pk & 255ull)], 1);
    srcs[p] = (int)(unsigned)(pk >> 32);
  }
}

// W (128x128 fp32 row-major, W[k][c]) -> Wt fp16 transposed: Wt[c][k]
__global__ void k_prepw(const float* __restrict__ W0, const float* __restrict__ W1,
                        const float* __restrict__ W2, _Float16* __restrict__ Wt) {
  int i = blockIdx.x * blockDim.x + threadIdx.x;   // 0..49151
  int m = i >> 14;
  int j = i & 16383;
  int c = j >> 7, k = j & 127;
  const float* W = (m == 0) ? W0 : (m == 1) ? W1 : W2;
  Wt[i] = (_Float16)W[k * 128 + c];
}

// ---------------- fp16 MFMA GEMM + dis-scale epilogue ----------------
// hws[r][:] = dis[r] * (relu?(in[r][:]) @ W), fp16, LINEAR [N][128] layout
// (round-6 proven; slicing experiments r7-r10 all regressed). Input loads are
// nontemporal: each row is read exactly once, don't evict hws from L2.

#define LDH 136   // padded halves per row -> conflict-free ds_read_b128

__global__ __launch_bounds__(256, 2)
void k_gemm(const float* __restrict__ in, int in_stride, int do_relu,
            const _Float16* __restrict__ Wt_g, const float* __restrict__ dis,
            _Float16* __restrict__ hws, int N) {
  __shared__ _Float16 Wt[128 * LDH];
  int t = threadIdx.x;
  int rbase = blockIdx.x * 128;

#pragma unroll
  for (int i = 0; i < 8; ++i) {
    int s = t + i * 256;
    int c = s >> 4, kh = s & 15;
    half8 w = ((const half8*)Wt_g)[s];
    *(half8*)&Wt[c * LDH + kh * 8] = w;
  }
  __syncthreads();

  int wv = t >> 6, lane = t & 63;
  int r0 = wv * 32;
  int lr = lane & 15, lg = lane >> 4;

  f4 acc[2][8];
#pragma unroll
  for (int fm = 0; fm < 2; ++fm)
#pragma unroll
    for (int fn = 0; fn < 8; ++fn) acc[fm][fn] = (f4){0.f, 0.f, 0.f, 0.f};

#pragma unroll
  for (int ks = 0; ks < 4; ++ks) {
    int k0 = ks * 32 + lg * 8;
    half8 a[8];
#pragma unroll
    for (int fn = 0; fn < 8; ++fn)
      a[fn] = *(const half8*)&Wt[(fn * 16 + lr) * LDH + k0];
#pragma unroll
    for (int fm = 0; fm < 2; ++fm) {
      int gr = rbase + r0 + fm * 16 + lr;
      float v0x = 0.f, v0y = 0.f, v0z = 0.f, v0w = 0.f;
      float v1x = 0.f, v1y = 0.f, v1z = 0.f, v1w = 0.f;
      if (gr < N) {
        const float* pr = in + (size_t)gr * in_stride + k0;
        v0x = __builtin_nontemporal_load(pr + 0);
        v0y = __builtin_nontemporal_load(pr + 1);
        v0z = __builtin_nontemporal_load(pr + 2);
        v0w = __builtin_nontemporal_load(pr + 3);
        v1x = __builtin_nontemporal_load(pr + 4);
        v1y = __builtin_nontemporal_load(pr + 5);
        v1z = __builtin_nontemporal_load(pr + 6);
        v1w = __builtin_nontemporal_load(pr + 7);
      }
      if (do_relu) {
        v0x = fmaxf(v0x, 0.f); v0y = fmaxf(v0y, 0.f);
        v0z = fmaxf(v0z, 0.f); v0w = fmaxf(v0w, 0.f);
        v1x = fmaxf(v1x, 0.f); v1y = fmaxf(v1y, 0.f);
        v1z = fmaxf(v1z, 0.f); v1w = fmaxf(v1w, 0.f);
      }
      half8 b;
      b[0] = (_Float16)v0x; b[1] = (_Float16)v0y;
      b[2] = (_Float16)v0z; b[3] = (_Float16)v0w;
      b[4] = (_Float16)v1x; b[5] = (_Float16)v1y;
      b[6] = (_Float16)v1z; b[7] = (_Float16)v1w;
#pragma unroll
      for (int fn = 0; fn < 8; ++fn)
        acc[fm][fn] = __builtin_amdgcn_mfma_f32_16x16x32_f16(a[fn], b, acc[fm][fn], 0, 0, 0);
    }
  }

#pragma unroll
  for (int fm = 0; fm < 2; ++fm) {
    int gr = rbase + r0 + fm * 16 + lr;
    if (gr >= N) continue;
    float dv = dis[gr];
#pragma unroll
    for (int fn = 0; fn < 8; ++fn) {
      f4 d = acc[fm][fn];
      half4 hv;
      hv[0] = (_Float16)(d[0] * dv);
      hv[1] = (_Float16)(d[1] * dv);
      hv[2] = (_Float16)(d[2] * dv);
      hv[3] = (_Float16)(d[3] * dv);
      *(half4*)(hws + (size_t)gr * 128 + fn * 16 + lg * 4) = hv;
    }
  }
}

// ---------------- aggregation: wave/node, fp16 gathers, 8-deep MLP ----------------
// Round-6 proven structure: one wave per node, lane = feature pair (256B
// coalesced row gather per edge), 8 gathers in flight. srcs/offs nontemporal
// (streams; don't evict the L3/L2-resident hws).

__global__ __launch_bounds__(256)
void k_agg(const _Float16* __restrict__ hws, const int* __restrict__ offs,
           const int* __restrict__ srcs, const float* __restrict__ dis,
           const float* __restrict__ bias, float* __restrict__ out,
           int N, int layer) {
  int wv = threadIdx.x >> 6, lane = threadIdx.x & 63;
  int v = blockIdx.x * 4 + wv;
  if (v >= N) return;

  const uint* h32 = (const uint*)hws;
  uint hv = h32[(size_t)v * 64 + lane];
  half2v h = __builtin_bit_cast(half2v, hv);
  float ax = (float)h[0], ay = (float)h[1];

  int e0 = __builtin_nontemporal_load(&offs[v]);
  int e1 = __builtin_nontemporal_load(&offs[v + 1]);
  int e = e0;
  for (; e + 8 <= e1; e += 8) {
    int s0 = __builtin_nontemporal_load(&srcs[e + 0]);
    int s1 = __builtin_nontemporal_load(&srcs[e + 1]);
    int s2 = __builtin_nontemporal_load(&srcs[e + 2]);
    int s3 = __builtin_nontemporal_load(&srcs[e + 3]);
    int s4 = __builtin_nontemporal_load(&srcs[e + 4]);
    int s5 = __builtin_nontemporal_load(&srcs[e + 5]);
    int s6 = __builtin_nontemporal_load(&srcs[e + 6]);
    int s7 = __builtin_nontemporal_load(&srcs[e + 7]);
    uint u0 = h32[(size_t)s0 * 64 + lane];
    uint u1 = h32[(size_t)s1 * 64 + lane];
    uint u2 = h32[(size_t)s2 * 64 + lane];
    uint u3 = h32[(size_t)s3 * 64 + lane];
    uint u4 = h32[(size_t)s4 * 64 + lane];
    uint u5 = h32[(size_t)s5 * 64 + lane];
    uint u6 = h32[(size_t)s6 * 64 + lane];
    uint u7 = h32[(size_t)s7 * 64 + lane];
    half2v p0 = __builtin_bit_cast(half2v, u0);
    half2v p1 = __builtin_bit_cast(half2v, u1);
    half2v p2 = __builtin_bit_cast(half2v, u2);
    half2v p3 = __builtin_bit_cast(half2v, u3);
    half2v p4 = __builtin_bit_cast(half2v, u4);
    half2v p5 = __builtin_bit_cast(half2v, u5);
    half2v p6 = __builtin_bit_cast(half2v, u6);
    half2v p7 = __builtin_bit_cast(half2v, u7);
    ax += (float)p0[0] + (float)p1[0] + (float)p2[0] + (float)p3[0]
        + (float)p4[0] + (float)p5[0] + (float)p6[0] + (float)p7[0];
    ay += (float)p0[1] + (float)p1[1] + (float)p2[1] + (float)p3[1]
        + (float)p4[1] + (float)p5[1] + (float)p6[1] + (float)p7[1];
  }
  for (; e < e1; ++e) {
    int s = __builtin_nontemporal_load(&srcs[e]);
    uint u = h32[(size_t)s * 64 + lane];
    half2v p = __builtin_bit_cast(half2v, u);
    ax += (float)p[0];
    ay += (float)p[1];
  }

  float dv = dis[v];
  float2 b = ((const float2*)bias)[lane];
  float2 o;
  o.x = fmaf(dv, ax, b.x);
  o.y = fmaf(dv, ay, b.y);
  *(float2*)(out + (size_t)v * 384 + layer * 128 + 2 * lane) = o;
}

// ---------------- launch ----------------

extern "C" void kernel_launch(void* const* d_in, const int* in_sizes, int n_in,
                              void* d_out, int out_size, void* d_ws, size_t ws_size,
                              hipStream_t stream) {
  const float* x  = (const float*)d_in[0];
  const int*   ei = (const int*)d_in[1];
  const float* W0 = (const float*)d_in[2];
  const float* b0 = (const float*)d_in[3];
  const float* W1 = (const float*)d_in[4];
  const float* b1 = (const float*)d_in[5];
  const float* W2 = (const float*)d_in[6];
  const float* b2 = (const float*)d_in[7];
  float* out = (float*)d_out;

  int N = in_sizes[0] / 128;
  int E = in_sizes[1] / 2;
  int nb = (N + 255) >> 8;                       // active buckets
  int chunk = (((E + NBLK - 1) / NBLK) + 255) & ~255;

  char* p = (char*)d_ws;
  auto alloc = [&](size_t sz) { char* r = p; p += (sz + 255) & ~(size_t)255; return r; };
  _Float16* hws  = (_Float16*)alloc((size_t)N * 128 * 2);
  float* dis     = (float*)alloc((size_t)N * 4);
  int*   offs    = (int*)alloc((size_t)(N + 1) * 4);
  int*   srcs    = (int*)alloc((size_t)E * 4);
  _Float16* Wt   = (_Float16*)alloc((size_t)3 * 128 * 128 * 2);
  int*   hb      = (int*)alloc((size_t)2 * NBLK * NBK * 4);
  int*   totals  = (int*)alloc((size_t)2 * NBK * 4);
  int*   boffs   = (int*)alloc((size_t)(NBK + 1) * 4);
  int*   soffs   = (int*)alloc((size_t)(NBK + 1) * 4);
  unsigned long long* pairs = (unsigned long long*)alloc((size_t)E * 8);
  unsigned char* srcb = (unsigned char*)alloc((size_t)E);

  k_bhist<<<NBLK, 256, 0, stream>>>(ei, E, chunk, hb);
  k_colscan<<<8, 256, 0, stream>>>(hb, totals);
  k_bscan2<<<1, 1024, 0, stream>>>(totals, boffs, soffs, offs, N, E);
  k_bscatter<<<NBLK, 256, 0, stream>>>(ei, E, chunk, hb, boffs, soffs, pairs, srcb);
  k_deg<<<nb, 256, 0, stream>>>(srcb, soffs, dis, N);
  k_fscatter<<<nb, 256, 0, stream>>>(pairs, boffs, offs, srcs, N);
  k_prepw<<<192, 256, 0, stream>>>(W0, W1, W2, Wt);

  int gG = (N + 127) / 128;
  int gA = (N + 3) / 4;

  // layer 0
  k_gemm<<<gG, 256, 0, stream>>>(x, 128, 0, Wt, dis, hws, N);
  k_agg<<<gA, 256, 0, stream>>>(hws, offs, srcs, dis, b0, out, N, 0);
  // layer 1: input = relu(out[:,0,:]) (stride 384)
  k_gemm<<<gG, 256, 0, stream>>>(out, 384, 1, Wt + 16384, dis, hws, N);
  k_agg<<<gA, 256, 0, stream>>>(hws, offs, srcs, dis, b1, out, N, 1);
  // layer 2: input = relu(out[:,1,:])
  k_gemm<<<gG, 256, 0, stream>>>(out + 128, 384, 1, Wt + 32768, dis, hws, N);
  k_agg<<<gA, 256, 0, stream>>>(hws, offs, srcs, dis, b2, out, N, 2);
}

// Round 12
// 385.855 us; speedup vs baseline: 3.1075x; 1.1332x over previous
//
#include <hip/hip_runtime.h>

typedef _Float16 half8 __attribute__((ext_vector_type(8)));
typedef _Float16 half4 __attribute__((ext_vector_type(4)));
typedef _Float16 half2v __attribute__((ext_vector_type(2)));
typedef float f4 __attribute__((ext_vector_type(4)));

#define NBK 1024     // bucket table size (256 nodes/bucket, supports N<=262144)
#define NBLK 128     // blocks in hist/scatter passes (fixed edge chunking)

// ---------------- graph preprocessing (NO global atomics) ----------------

__global__ __launch_bounds__(256)
void k_bhist(const int* __restrict__ ei, int E, int chunk,
             int* __restrict__ hb) {
  __shared__ int hd[NBK], hs[NBK];
  int t = threadIdx.x, blk = blockIdx.x;
  for (int i = t; i < NBK; i += 256) { hd[i] = 0; hs[i] = 0; }
  __syncthreads();
  int start = blk * chunk, end = min(E, start + chunk);
  for (int i = start + t; i < end; i += 256) {
    int dst = ei[i];
    int src = ei[E + i];
    atomicAdd(&hd[dst >> 8], 1);
    atomicAdd(&hs[src >> 8], 1);
  }
  __syncthreads();
  for (int i = t; i < NBK; i += 256) {
    hb[blk * NBK + i] = hd[i];
    hb[(NBLK + blk) * NBK + i] = hs[i];
  }
}

__global__ void k_colscan(int* __restrict__ hb, int* __restrict__ totals) {
  int tid = blockIdx.x * 256 + threadIdx.x;      // 0..2047
  int* tab = hb + (tid >> 10) * (NBLK * NBK);
  int j = tid & (NBK - 1);
  int run = 0;
  for (int b = 0; b < NBLK; ++b) {
    int idx = b * NBK + j;
    int v = tab[idx];
    tab[idx] = run;
    run += v;
  }
  totals[tid] = run;
}

__global__ void k_bscan2(const int* __restrict__ totals, int* __restrict__ boffs,
                         int* __restrict__ soffs, int* __restrict__ offs,
                         int N, int E) {
  __shared__ int s[NBK];
  int t = threadIdx.x;                            // 1024 threads
  int v = totals[t];
  s[t] = v;
  __syncthreads();
  for (int off = 1; off < NBK; off <<= 1) {
    int x = (t >= off) ? s[t - off] : 0;
    __syncthreads();
    s[t] += x;
    __syncthreads();
  }
  boffs[t] = s[t] - v;
  if (t == NBK - 1) boffs[NBK] = s[t];
  __syncthreads();
  int v2 = totals[NBK + t];
  s[t] = v2;
  __syncthreads();
  for (int off = 1; off < NBK; off <<= 1) {
    int x = (t >= off) ? s[t - off] : 0;
    __syncthreads();
    s[t] += x;
    __syncthreads();
  }
  soffs[t] = s[t] - v2;
  if (t == NBK - 1) soffs[NBK] = s[t];
  if (t == 0) offs[N] = E;
}

__global__ __launch_bounds__(256)
void k_bscatter(const int* __restrict__ ei, int E, int chunk,
                const int* __restrict__ hb, const int* __restrict__ boffs,
                const int* __restrict__ soffs,
                unsigned long long* __restrict__ pairs,
                unsigned char* __restrict__ srcb) {
  __shared__ int based[NBK], posd[NBK], bases[NBK], poss[NBK];
  int t = threadIdx.x, blk = blockIdx.x;
  for (int i = t; i < NBK; i += 256) {
    based[i] = hb[blk * NBK + i] + boffs[i];
    posd[i] = 0;
    bases[i] = hb[(NBLK + blk) * NBK + i] + soffs[i];
    poss[i] = 0;
  }
  __syncthreads();
  int start = blk * chunk, end = min(E, start + chunk);
  for (int i = start + t; i < end; i += 256) {
    int dst = ei[i];
    int src = ei[E + i];
    int bd = dst >> 8, bs = src >> 8;
    int p = atomicAdd(&posd[bd], 1);
    pairs[based[bd] + p] =
        ((unsigned long long)(unsigned)src << 32) | (unsigned)dst;
    int q = atomicAdd(&poss[bs], 1);
    srcb[bases[bs] + q] = (unsigned char)(src & 255);
  }
}

__global__ __launch_bounds__(256)
void k_deg(const unsigned char* __restrict__ srcb, const int* __restrict__ soffs,
           float* __restrict__ dis, int N) {
  __shared__ int h[256];
  int b = blockIdx.x, t = threadIdx.x;
  h[t] = 0;
  __syncthreads();
  int lo = soffs[b], hi = soffs[b + 1];
  for (int i = lo + t; i < hi; i += 256) atomicAdd(&h[srcb[i]], 1);
  __syncthreads();
  int v = (b << 8) + t;
  if (v < N) dis[v] = rsqrtf((float)(h[t] + 1));
}

__global__ __launch_bounds__(256)
void k_fscatter(const unsigned long long* __restrict__ pairs,
                const int* __restrict__ boffs,
                int* __restrict__ offs, int* __restrict__ srcs, int N) {
  __shared__ int h[256], sc[256], cur[256];
  int b = blockIdx.x, t = threadIdx.x;
  h[t] = 0;
  __syncthreads();
  int pl = boffs[b], ph = boffs[b + 1];
  for (int i = pl + t; i < ph; i += 256)
    atomicAdd(&h[(int)(pairs[i] & 255ull)], 1);
  __syncthreads();
  sc[t] = h[t];
  __syncthreads();
  for (int off = 1; off < 256; off <<= 1) {
    int x = (t >= off) ? sc[t - off] : 0;
    __syncthreads();
    sc[t] += x;
    __syncthreads();
  }
  int excl = sc[t] - h[t];
  int v = (b << 8) + t;
  if (v < N) offs[v] = pl + excl;
  cur[t] = pl + excl;
  __syncthreads();
  for (int i = pl + t; i < ph; i += 256) {
    unsigned long long pk = pairs[i];
    int p = atomicAdd(&cur[(int)(pk & 255ull)], 1);
    srcs[p] = (int)(unsigned)(pk >> 32);
  }
}

// W (128x128 fp32 row-major, W[k][c]) -> Wt fp16 transposed: Wt[c][k]
__global__ void k_prepw(const float* __restrict__ W0, const float* __restrict__ W1,
                        const float* __restrict__ W2, _Float16* __restrict__ Wt) {
  int i = blockIdx.x * blockDim.x + threadIdx.x;   // 0..49151
  int m = i >> 14;
  int j = i & 16383;
  int c = j >> 7, k = j & 127;
  const float* W = (m == 0) ? W0 : (m == 1) ? W1 : W2;
  Wt[i] = (_Float16)W[k * 128 + c];
}

// ---------------- fp16 MFMA GEMM + dis-scale epilogue ----------------
// hws[r][:] = dis[r] * (relu?(in[r][:]) @ W), fp16, linear [N][128] layout.
// (Round-6 proven body; r11's nontemporal input loads scalarized the loads
// and cost ~17us/dispatch — reverted to plain float4.)

#define LDH 136   // padded halves per row -> conflict-free ds_read_b128

__global__ __launch_bounds__(256, 2)
void k_gemm(const float* __restrict__ in, int in_stride, int do_relu,
            const _Float16* __restrict__ Wt_g, const float* __restrict__ dis,
            _Float16* __restrict__ hws, int N) {
  __shared__ _Float16 Wt[128 * LDH];
  int t = threadIdx.x;
  int rbase = blockIdx.x * 128;

#pragma unroll
  for (int i = 0; i < 8; ++i) {
    int s = t + i * 256;
    int c = s >> 4, kh = s & 15;
    half8 w = ((const half8*)Wt_g)[s];
    *(half8*)&Wt[c * LDH + kh * 8] = w;
  }
  __syncthreads();

  int wv = t >> 6, lane = t & 63;
  int r0 = wv * 32;
  int lr = lane & 15, lg = lane >> 4;

  f4 acc[2][8];
#pragma unroll
  for (int fm = 0; fm < 2; ++fm)
#pragma unroll
    for (int fn = 0; fn < 8; ++fn) acc[fm][fn] = (f4){0.f, 0.f, 0.f, 0.f};

#pragma unroll
  for (int ks = 0; ks < 4; ++ks) {
    int k0 = ks * 32 + lg * 8;
    half8 a[8];
#pragma unroll
    for (int fn = 0; fn < 8; ++fn)
      a[fn] = *(const half8*)&Wt[(fn * 16 + lr) * LDH + k0];
#pragma unroll
    for (int fm = 0; fm < 2; ++fm) {
      int gr = rbase + r0 + fm * 16 + lr;
      float4 v0 = make_float4(0.f, 0.f, 0.f, 0.f);
      float4 v1 = make_float4(0.f, 0.f, 0.f, 0.f);
      if (gr < N) {
        const float* pr = in + (size_t)gr * in_stride + k0;
        v0 = *(const float4*)pr;
        v1 = *(const float4*)(pr + 4);
      }
      if (do_relu) {
        v0.x = fmaxf(v0.x, 0.f); v0.y = fmaxf(v0.y, 0.f);
        v0.z = fmaxf(v0.z, 0.f); v0.w = fmaxf(v0.w, 0.f);
        v1.x = fmaxf(v1.x, 0.f); v1.y = fmaxf(v1.y, 0.f);
        v1.z = fmaxf(v1.z, 0.f); v1.w = fmaxf(v1.w, 0.f);
      }
      half8 b;
      b[0] = (_Float16)v0.x; b[1] = (_Float16)v0.y;
      b[2] = (_Float16)v0.z; b[3] = (_Float16)v0.w;
      b[4] = (_Float16)v1.x; b[5] = (_Float16)v1.y;
      b[6] = (_Float16)v1.z; b[7] = (_Float16)v1.w;
#pragma unroll
      for (int fn = 0; fn < 8; ++fn)
        acc[fm][fn] = __builtin_amdgcn_mfma_f32_16x16x32_f16(a[fn], b, acc[fm][fn], 0, 0, 0);
    }
  }

#pragma unroll
  for (int fm = 0; fm < 2; ++fm) {
    int gr = rbase + r0 + fm * 16 + lr;
    if (gr >= N) continue;
    float dv = dis[gr];
#pragma unroll
    for (int fn = 0; fn < 8; ++fn) {
      f4 d = acc[fm][fn];
      half4 hv;
      hv[0] = (_Float16)(d[0] * dv);
      hv[1] = (_Float16)(d[1] * dv);
      hv[2] = (_Float16)(d[2] * dv);
      hv[3] = (_Float16)(d[3] * dv);
      *(half4*)(hws + (size_t)gr * 128 + fn * 16 + lg * 4) = hv;
    }
  }
}

// ---------------- aggregation: wave/node, fp16 gathers, 8-deep MLP ----------------
// Round-6 proven structure. FETCH measured at 204MB = 8 XCDs x 25.6MB hws =
// the compulsory per-XCD L2 fill floor; runs at the ~2.7 TB/s random-fill
// ceiling. Structural optimum for this access pattern.

__global__ __launch_bounds__(256)
void k_agg(const _Float16* __restrict__ hws, const int* __restrict__ offs,
           const int* __restrict__ srcs, const float* __restrict__ dis,
           const float* __restrict__ bias, float* __restrict__ out,
           int N, int layer) {
  int wv = threadIdx.x >> 6, lane = threadIdx.x & 63;
  int v = blockIdx.x * 4 + wv;
  if (v >= N) return;

  const uint* h32 = (const uint*)hws;
  uint hv = h32[(size_t)v * 64 + lane];
  half2v h = __builtin_bit_cast(half2v, hv);
  float ax = (float)h[0], ay = (float)h[1];

  int e0 = offs[v], e1 = offs[v + 1];
  int e = e0;
  for (; e + 8 <= e1; e += 8) {
    int s0 = srcs[e + 0], s1 = srcs[e + 1], s2 = srcs[e + 2], s3 = srcs[e + 3];
    int s4 = srcs[e + 4], s5 = srcs[e + 5], s6 = srcs[e + 6], s7 = srcs[e + 7];
    uint u0 = h32[(size_t)s0 * 64 + lane];
    uint u1 = h32[(size_t)s1 * 64 + lane];
    uint u2 = h32[(size_t)s2 * 64 + lane];
    uint u3 = h32[(size_t)s3 * 64 + lane];
    uint u4 = h32[(size_t)s4 * 64 + lane];
    uint u5 = h32[(size_t)s5 * 64 + lane];
    uint u6 = h32[(size_t)s6 * 64 + lane];
    uint u7 = h32[(size_t)s7 * 64 + lane];
    half2v p0 = __builtin_bit_cast(half2v, u0);
    half2v p1 = __builtin_bit_cast(half2v, u1);
    half2v p2 = __builtin_bit_cast(half2v, u2);
    half2v p3 = __builtin_bit_cast(half2v, u3);
    half2v p4 = __builtin_bit_cast(half2v, u4);
    half2v p5 = __builtin_bit_cast(half2v, u5);
    half2v p6 = __builtin_bit_cast(half2v, u6);
    half2v p7 = __builtin_bit_cast(half2v, u7);
    ax += (float)p0[0] + (float)p1[0] + (float)p2[0] + (float)p3[0]
        + (float)p4[0] + (float)p5[0] + (float)p6[0] + (float)p7[0];
    ay += (float)p0[1] + (float)p1[1] + (float)p2[1] + (float)p3[1]
        + (float)p4[1] + (float)p5[1] + (float)p6[1] + (float)p7[1];
  }
  for (; e < e1; ++e) {
    int s = srcs[e];
    uint u = h32[(size_t)s * 64 + lane];
    half2v p = __builtin_bit_cast(half2v, u);
    ax += (float)p[0];
    ay += (float)p[1];
  }

  float dv = dis[v];
  float2 b = ((const float2*)bias)[lane];
  float2 o;
  o.x = fmaf(dv, ax, b.x);
  o.y = fmaf(dv, ay, b.y);
  *(float2*)(out + (size_t)v * 384 + layer * 128 + 2 * lane) = o;
}

// ---------------- launch ----------------

extern "C" void kernel_launch(void* const* d_in, const int* in_sizes, int n_in,
                              void* d_out, int out_size, void* d_ws, size_t ws_size,
                              hipStream_t stream) {
  const float* x  = (const float*)d_in[0];
  const int*   ei = (const int*)d_in[1];
  const float* W0 = (const float*)d_in[2];
  const float* b0 = (const float*)d_in[3];
  const float* W1 = (const float*)d_in[4];
  const float* b1 = (const float*)d_in[5];
  const float* W2 = (const float*)d_in[6];
  const float* b2 = (const float*)d_in[7];
  float* out = (float*)d_out;

  int N = in_sizes[0] / 128;
  int E = in_sizes[1] / 2;
  int nb = (N + 255) >> 8;                       // active buckets
  int chunk = (((E + NBLK - 1) / NBLK) + 255) & ~255;

  char* p = (char*)d_ws;
  auto alloc = [&](size_t sz) { char* r = p; p += (sz + 255) & ~(size_t)255; return r; };
  _Float16* hws  = (_Float16*)alloc((size_t)N * 128 * 2);
  float* dis     = (float*)alloc((size_t)N * 4);
  int*   offs    = (int*)alloc((size_t)(N + 1) * 4);
  int*   srcs    = (int*)alloc((size_t)E * 4);
  _Float16* Wt   = (_Float16*)alloc((size_t)3 * 128 * 128 * 2);
  int*   hb      = (int*)alloc((size_t)2 * NBLK * NBK * 4);
  int*   totals  = (int*)alloc((size_t)2 * NBK * 4);
  int*   boffs   = (int*)alloc((size_t)(NBK + 1) * 4);
  int*   soffs   = (int*)alloc((size_t)(NBK + 1) * 4);
  unsigned long long* pairs = (unsigned long long*)alloc((size_t)E * 8);
  unsigned char* srcb = (unsigned char*)alloc((size_t)E);

  k_bhist<<<NBLK, 256, 0, stream>>>(ei, E, chunk, hb);
  k_colscan<<<8, 256, 0, stream>>>(hb, totals);
  k_bscan2<<<1, 1024, 0, stream>>>(totals, boffs, soffs, offs, N, E);
  k_bscatter<<<NBLK, 256, 0, stream>>>(ei, E, chunk, hb, boffs, soffs, pairs, srcb);
  k_deg<<<nb, 256, 0, stream>>>(srcb, soffs, dis, N);
  k_fscatter<<<nb, 256, 0, stream>>>(pairs, boffs, offs, srcs, N);
  k_prepw<<<192, 256, 0, stream>>>(W0, W1, W2, Wt);

  int gG = (N + 127) / 128;
  int gA = (N + 3) / 4;

  // layer 0
  k_gemm<<<gG, 256, 0, stream>>>(x, 128, 0, Wt, dis, hws, N);
  k_agg<<<gA, 256, 0, stream>>>(hws, offs, srcs, dis, b0, out, N, 0);
  // layer 1: input = relu(out[:,0,:]) (stride 384)
  k_gemm<<<gG, 256, 0, stream>>>(out, 384, 1, Wt + 16384, dis, hws, N);
  k_agg<<<gA, 256, 0, stream>>>(hws, offs, srcs, dis, b1, out, N, 1);
  // layer 2: input = relu(out[:,1,:])
  k_gemm<<<gG, 256, 0, stream>>>(out + 128, 384, 1, Wt + 32768, dis, hws, N);
  k_agg<<<gA, 256, 0, stream>>>(hws, offs, srcs, dis, b2, out, N, 2);
}